// Round 1
// 879.926 us; speedup vs baseline: 1.2633x; 1.2633x over previous
//
#include <hip/hip_runtime.h>

static constexpr int B_ = 32, C_ = 256, K_ = 64, H_ = 64, W_ = 64;
static constexpr int N_ = H_ * W_;      // 4096
static constexpr int IN_ = C_ + K_;     // 320

// ---------------- bf16 helpers (raw short storage) ----------------
__device__ __forceinline__ short f2bs(float f) {
  unsigned u = __builtin_bit_cast(unsigned, f);
  u += 0x7fffu + ((u >> 16) & 1u);
  return (short)(u >> 16);
}
__device__ __forceinline__ float bs2f(short s) {
  unsigned u = ((unsigned)(unsigned short)s) << 16;
  return __builtin_bit_cast(float, u);
}

typedef __attribute__((ext_vector_type(8))) short s8v;
typedef __attribute__((ext_vector_type(4))) short s4v;
typedef __attribute__((ext_vector_type(4))) float f4v;

// ---------------- workspace layout (bytes) ----------------
static constexpr long long OB_XT   = 0;
static constexpr long long OB_ZT   = 67108864LL;
static constexpr long long OB_DWS  = 0;
static constexpr long long OB_DT   = 83886080LL;
static constexpr long long OB_PX   = 83886080LL;
static constexpr long long OB_CORR = 150994944LL;
static constexpr long long OB_G    = 150994944LL;
static constexpr long long OB_T1   = 159383552LL;
static constexpr long long OB_S    = 167772160LL;
static constexpr long long OB_PXT  = 234881024LL;
static constexpr long long OB_ATT  = 301989888LL;
static constexpr long long OB_M2   = OB_ATT + 8388608LL;
static constexpr long long OB_M3   = OB_M2 + 8388608LL;
static constexpr long long OB_MISC = OB_M3 + 8388608LL;          // 318.8MB
static constexpr long long OB_PWW  = OB_MISC;                    // 320*256*2
static constexpr long long OB_INPW = OB_PWW + 262144LL;
static constexpr long long OB_M3B  = OB_INPW + 262144LL;         // 4MB bf16
static constexpr long long OB_R    = OB_M3B + 4194304LL;         // fp32 vecs
static constexpr long long OB_U    = OB_R + 32768LL;
static constexpr long long OB_W2   = OB_U + 32768LL;
static constexpr long long OB_M2B  = OB_W2 + 32768LL;
static constexpr long long OB_B3   = OB_M2B + 32768LL;
static constexpr long long OB_BNS  = OB_B3 + 32768LL;
static constexpr long long OB_BNH  = OB_BNS + 2048LL;

// ---------------- async global->LDS ----------------
__device__ __forceinline__ void gload16(const void* g, void* l) {
  __builtin_amdgcn_global_load_lds((const __attribute__((address_space(1))) void*)g,
                                   (__attribute__((address_space(3))) void*)l, 16, 0, 0);
}

// ===========================================================================
// MFMA bf16 GEMM: D[m,n] = sum_k A[m,k] * Bt[n,k]
// ===========================================================================
template <int BN, int SPLIT, int EPI>
__global__ __launch_bounds__(256) void mgemm(
    const short* __restrict__ A, int lda, long long sA,
    const short* __restrict__ Bt, int ldb, long long sB,
    void* __restrict__ Cv, int ldc, long long sC,
    int Kd,
    const float* __restrict__ biasc, const float* __restrict__ shf,
    const float* __restrict__ biasr,
    const short* __restrict__ resT, int ldrt, long long sRT,
    short* __restrict__ outT, int ldt, long long sT)
{
  constexpr int JT = BN / 32;         // MFMA n-tiles per wave
  __shared__ short As[128 * 32];
  __shared__ short Bs[BN * 32];

  const int t = threadIdx.x;
  const int wv = t >> 6;
  const int lane = t & 63, quad = lane >> 4, lr = lane & 15;
  const int wm = wv >> 1, wn = wv & 1;
  const int m_off = wm * 64, n_off = wn * (BN / 2);

  const int n0 = blockIdx.x * BN;
  const int m0 = blockIdx.y * 128;
  const int bz = (SPLIT == 1) ? blockIdx.z : (blockIdx.z / SPLIT);
  const int sp = (SPLIT == 1) ? 0 : (blockIdx.z % SPLIT);
  const int koff = sp * Kd;

  A += (long long)bz * sA;
  Bt += (long long)bz * sB;

  const int arow = t >> 2;            // 0..63
  const int acol = (t & 3) << 3;      // element offset (8 shorts = 16B)

  f4v acc[4][JT];
#pragma unroll
  for (int i = 0; i < 4; ++i)
#pragma unroll
    for (int j = 0; j < JT; ++j) acc[i][j] = (f4v)0.f;

  for (int k0 = 0; k0 < Kd; k0 += 32) {
#pragma unroll
    for (int rr = 0; rr < 2; ++rr) {
      const short* gp = A + (long long)(m0 + rr * 64 + arow) * lda + koff + k0 + acol;
      gload16(gp, (char*)As + rr * 4096 + wv * 1024);
    }
#pragma unroll
    for (int rr = 0; rr < BN / 64; ++rr) {
      const short* gp = Bt + (long long)(n0 + rr * 64 + arow) * ldb + koff + k0 + acol;
      gload16(gp, (char*)Bs + rr * 4096 + wv * 1024);
    }
    __syncthreads();

    s8v af[4], bfv[JT];
#pragma unroll
    for (int i = 0; i < 4; ++i)
      af[i] = *(const s8v*)&As[(m_off + i * 16 + lr) * 32 + quad * 8];
#pragma unroll
    for (int j = 0; j < JT; ++j)
      bfv[j] = *(const s8v*)&Bs[(n_off + j * 16 + lr) * 32 + quad * 8];
#pragma unroll
    for (int i = 0; i < 4; ++i)
#pragma unroll
      for (int j = 0; j < JT; ++j)
        acc[i][j] = __builtin_amdgcn_mfma_f32_16x16x32_bf16(af[i], bfv[j], acc[i][j], 0, 0, 0);
    __syncthreads();
  }

  // epilogue
  float* Cf = (float*)Cv;
  short* Cb = (short*)Cv;
  if (EPI & 1) Cb += (long long)bz * sC; else Cf += (long long)bz * sC;
  if (EPI & 16) resT += (long long)bz * sRT;
  if (EPI & 32) outT += (long long)bz * sT;

#pragma unroll
  for (int i = 0; i < 4; ++i) {
    const int mb = m0 + m_off + i * 16 + quad * 4;
#pragma unroll
    for (int j = 0; j < JT; ++j) {
      const int n = n0 + n_off + j * 16 + lr;
      float vr[4];
#pragma unroll
      for (int r = 0; r < 4; ++r) {
        float v = acc[i][j][r];
        if (EPI & 2) v += biasc[n];
        if (EPI & 4) v = fmaxf(fmaf(v, biasc[n], shf[n]), 0.f);
        if (EPI & 8) v += biasr[bz * 256 + mb + r];
        vr[r] = v;
      }
      if (EPI & 16) {
        s4v rv = *(const s4v*)(resT + (long long)n * ldrt + mb);
#pragma unroll
        for (int r = 0; r < 4; ++r) vr[r] += bs2f(rv[r]);
      }
      if (EPI & 32) {
        s4v tv;
#pragma unroll
        for (int r = 0; r < 4; ++r) tv[r] = f2bs(vr[r]);
        *(s4v*)(outT + (long long)n * ldt + mb) = tv;
      }
#pragma unroll
      for (int r = 0; r < 4; ++r) {
        if (EPI & 64) atomicAdd(&Cf[(long long)(mb + r) * ldc + n], vr[r]);
        else if (EPI & 1) Cb[(long long)(mb + r) * ldc + n] = f2bs(vr[r]);
        else Cf[(long long)(mb + r) * ldc + n] = vr[r];
      }
    }
  }
}

// ---------------- transpose-cast: in fp32 [R, Cc] -> out bf16 [Cc, R] ----------------
__global__ __launch_bounds__(256) void tcast(const float* __restrict__ in,
                                             short* __restrict__ out,
                                             int R, int Cc, long long sIn, long long sOut)
{
  __shared__ float tile[32][33];
  const int b = blockIdx.z;
  const int r0 = blockIdx.y * 32, c0 = blockIdx.x * 32;
  in += (long long)b * sIn;
  out += (long long)b * sOut;
  const int tx = threadIdx.x & 31, ty = threadIdx.x >> 5;   // ty 0..7
#pragma unroll
  for (int i = 0; i < 32; i += 8)
    tile[ty + i][tx] = in[(long long)(r0 + ty + i) * Cc + c0 + tx];
  __syncthreads();
#pragma unroll
  for (int i = 0; i < 32; i += 8)
    out[(long long)(c0 + ty + i) * R + r0 + tx] = f2bs(tile[tx][ty + i]);
}

// ---------------- flat fp32 -> bf16 cast ----------------
__global__ void castw(const float* __restrict__ in, short* __restrict__ out, long long n)
{
  long long i = (long long)blockIdx.x * 256 + threadIdx.x;
  if (i < n) out[i] = f2bs(in[i]);
}

// ===========================================================================
// depthwise 3x3 over concat([corr(64), d(256)]), [N,ch] layout — VECTORIZED.
// Each thread: 8 channels x 1 pixel. 9x s8v (16B) loads + 72 FMAs + 1x 16B store.
// Weights staged transposed in LDS: wl[tap*320 + ch] so per-tap weights for
// 8 consecutive channels are two float4 LDS reads.
// grid: (N_*40/256 = 640, B_), block 256.
// ===========================================================================
__global__ __launch_bounds__(256) void dwconv3(const short* __restrict__ corr,
                                               const short* __restrict__ dt,
                                               const float* __restrict__ wgt,
                                               const float* __restrict__ bias,
                                               short* __restrict__ outp)
{
  __shared__ __align__(16) float wl[9 * IN_];
  __shared__ __align__(16) float bl[IN_];
  const int tid = threadIdx.x;
  for (int i = tid; i < 9 * IN_; i += 256) {
    const int ch = i / 9, tap = i % 9;
    wl[tap * IN_ + ch] = wgt[i];
  }
  for (int i = tid; i < IN_; i += 256) bl[i] = bias[i];
  __syncthreads();

  const int id = blockIdx.x * 256 + tid;
  const int b = blockIdx.y;
  const int cg = id % 40;              // channel group (8 ch each)
  const int pix = id / 40;             // 0..4095
  const int y = pix >> 6, x = pix & 63;
  const int ch0 = cg * 8;

  const short* base;
  int ldch, c0;
  if (cg < 8) { base = corr + (long long)b * N_ * K_; ldch = K_; c0 = ch0; }
  else        { base = dt   + (long long)b * N_ * C_; ldch = C_; c0 = ch0 - K_; }

  float acc[8];
  {
    float4 bv0 = *(const float4*)&bl[ch0];
    float4 bv1 = *(const float4*)&bl[ch0 + 4];
    acc[0] = bv0.x; acc[1] = bv0.y; acc[2] = bv0.z; acc[3] = bv0.w;
    acc[4] = bv1.x; acc[5] = bv1.y; acc[6] = bv1.z; acc[7] = bv1.w;
  }

#pragma unroll
  for (int dy = -1; dy <= 1; ++dy) {
    const int yy = y + dy;
    if (yy < 0 || yy >= H_) continue;
#pragma unroll
    for (int dx = -1; dx <= 1; ++dx) {
      const int xx = x + dx;
      if (xx < 0 || xx >= W_) continue;
      const int tap = (dy + 1) * 3 + (dx + 1);
      s8v v = *(const s8v*)(base + (long long)(yy * W_ + xx) * ldch + c0);
      float4 wa = *(const float4*)&wl[tap * IN_ + ch0];
      float4 wb = *(const float4*)&wl[tap * IN_ + ch0 + 4];
      acc[0] = fmaf(wa.x, bs2f(v[0]), acc[0]);
      acc[1] = fmaf(wa.y, bs2f(v[1]), acc[1]);
      acc[2] = fmaf(wa.z, bs2f(v[2]), acc[2]);
      acc[3] = fmaf(wa.w, bs2f(v[3]), acc[3]);
      acc[4] = fmaf(wb.x, bs2f(v[4]), acc[4]);
      acc[5] = fmaf(wb.y, bs2f(v[5]), acc[5]);
      acc[6] = fmaf(wb.z, bs2f(v[6]), acc[6]);
      acc[7] = fmaf(wb.w, bs2f(v[7]), acc[7]);
    }
  }

  s8v o;
#pragma unroll
  for (int j = 0; j < 8; ++j) o[j] = f2bs(acc[j]);
  *(s8v*)(outp + ((long long)b * N_ + pix) * IN_ + ch0) = o;
}

// ---------------- column sums of px_b [N, C] -> r[b, c] (atomic) ----------------
__global__ void colsum(const short* __restrict__ px, float* __restrict__ r)
{
  const int b = blockIdx.y, c = threadIdx.x, chunk = blockIdx.x;
  const short* p = px + (long long)b * N_ * C_ + (long long)chunk * 512 * C_;
  float s = 0.f;
  for (int n = 0; n < 512; ++n) s += bs2f(p[(long long)n * C_ + c]);
  atomicAdd(&r[b * C_ + c], s);
}

// ===========================================================================
// fp32 64x64 tiled GEMM for the small C x C products
// ===========================================================================
template <int TA, int TB, int EPI>
__global__ __launch_bounds__(256) void gemm64(
    const float* __restrict__ A, int lda, long long sA,
    const float* __restrict__ B, int ldb, long long sB,
    float* __restrict__ Cout, int ldc, long long sC,
    int Kd, float alpha)
{
  const int n0 = blockIdx.x * 64;
  const int m0 = blockIdx.y * 64;
  const int bz = blockIdx.z;
  A += (long long)bz * sA;
  B += (long long)bz * sB;
  Cout += (long long)bz * sC;

  __shared__ __align__(16) float As[16][68];
  __shared__ __align__(16) float Bs[16][68];
  const int tid = threadIdx.x;
  const int tx = tid & 15, ty = tid >> 4;
  float acc[4][4] = {};

  for (int k0 = 0; k0 < Kd; k0 += 16) {
    if (TA == 0) {
      const int m = tid >> 2, k4 = (tid & 3) << 2;
      float4 v = *(const float4*)(A + (long long)(m0 + m) * lda + k0 + k4);
      As[k4 + 0][m] = v.x; As[k4 + 1][m] = v.y;
      As[k4 + 2][m] = v.z; As[k4 + 3][m] = v.w;
    } else {
      const int kk = tid >> 4, m4 = (tid & 15) << 2;
      *(float4*)&As[kk][m4] = *(const float4*)(A + (long long)(k0 + kk) * lda + m0 + m4);
    }
    if (TB == 0) {
      const int kk = tid >> 4, n4 = (tid & 15) << 2;
      *(float4*)&Bs[kk][n4] = *(const float4*)(B + (long long)(k0 + kk) * ldb + n0 + n4);
    } else {
      const int n = tid >> 2, k4 = (tid & 3) << 2;
      float4 v = *(const float4*)(B + (long long)(n0 + n) * ldb + k0 + k4);
      Bs[k4 + 0][n] = v.x; Bs[k4 + 1][n] = v.y;
      Bs[k4 + 2][n] = v.z; Bs[k4 + 3][n] = v.w;
    }
    __syncthreads();
#pragma unroll
    for (int kk = 0; kk < 16; ++kk) {
      float4 av = *(const float4*)&As[kk][ty << 2];
      float4 bv = *(const float4*)&Bs[kk][tx << 2];
      float a[4] = {av.x, av.y, av.z, av.w};
      float b[4] = {bv.x, bv.y, bv.z, bv.w};
#pragma unroll
      for (int i = 0; i < 4; ++i)
#pragma unroll
        for (int j = 0; j < 4; ++j) acc[i][j] = fmaf(a[i], b[j], acc[i][j]);
    }
    __syncthreads();
  }
#pragma unroll
  for (int i = 0; i < 4; ++i)
#pragma unroll
    for (int j = 0; j < 4; ++j) {
      float v = acc[i][j];
      if (EPI & 8) v *= alpha;
      Cout[(long long)(m0 + (ty << 2) + i) * ldc + n0 + (tx << 2) + j] = v;
    }
}

// ---------------- small fused kernels ----------------
__global__ void bncoef(const float* __restrict__ pwb, const float* __restrict__ g,
                       const float* __restrict__ bt, const float* __restrict__ mn,
                       const float* __restrict__ vr, float* __restrict__ scl,
                       float* __restrict__ shf)
{
  const int c = threadIdx.x;
  const float inv = rsqrtf(vr[c] + 1e-5f);
  const float sc = g[c] * inv;
  scl[c] = sc;
  shf[c] = (pwb[c] - mn[c]) * sc + bt[c];
}

__global__ void uwker(const float* __restrict__ qw, const float* __restrict__ kw,
                      const float* __restrict__ r, float* __restrict__ u,
                      float* __restrict__ w)
{
  const int b = blockIdx.x, c = threadIdx.x;
  __shared__ float rl[256];
  rl[c] = r[b * C_ + c];
  __syncthreads();
  float su = 0.f, sw = 0.f;
  for (int f = 0; f < C_; ++f) {
    const float rv = rl[f];
    su = fmaf(qw[c * C_ + f], rv, su);
    sw = fmaf(kw[c * C_ + f], rv, sw);
  }
  u[b * C_ + c] = su;
  w[b * C_ + c] = sw;
}

__global__ void fixsoftmax(float* __restrict__ att, const float* __restrict__ u,
                           const float* __restrict__ w, const float* __restrict__ qb,
                           const float* __restrict__ kb)
{
  const int c = blockIdx.x, b = blockIdx.y, d = threadIdx.x;
  const long long base = ((long long)b * C_ + c) * (long long)C_;
  const float qbc = qb[c];
  float val = att[base + d] +
              0.0625f * (u[b * C_ + c] * kb[d] + qbc * w[b * C_ + d] +
                         (float)N_ * qbc * kb[d]);
  __shared__ float red[256];
  red[d] = val;
  __syncthreads();
  for (int k = 128; k > 0; k >>= 1) {
    if (d < k) red[d] = fmaxf(red[d], red[d + k]);
    __syncthreads();
  }
  const float mx = red[0];
  __syncthreads();
  const float e = expf(val - mx);
  red[d] = e;
  __syncthreads();
  for (int k = 128; k > 0; k >>= 1) {
    if (d < k) red[d] += red[d + k];
    __syncthreads();
  }
  att[base + d] = e / red[0];
}

__global__ void m2bker(const float* __restrict__ att, const float* __restrict__ vb,
                       float* __restrict__ m2b)
{
  const int b = blockIdx.x, d = threadIdx.x;
  const float* a = att + (long long)b * C_ * C_;
  float s = 0.f;
  for (int c = 0; c < C_; ++c) s = fmaf(a[c * C_ + d], vb[c], s);
  m2b[b * C_ + d] = s;
}

__global__ void b3ker(const float* __restrict__ opw, const float* __restrict__ m2b,
                      const float* __restrict__ opb, float* __restrict__ b3)
{
  const int b = blockIdx.x, o = threadIdx.x;
  __shared__ float m[256];
  m[o] = m2b[b * C_ + o];
  __syncthreads();
  float s = opb[o];
  for (int d = 0; d < C_; ++d) s = fmaf(opw[o * C_ + d], m[d], s);
  b3[b * C_ + o] = s;
}

// ===========================================================================
extern "C" void kernel_launch(void* const* d_in, const int* in_sizes, int n_in,
                              void* d_out, int out_size, void* d_ws, size_t ws_size,
                              hipStream_t stream)
{
  (void)in_sizes; (void)n_in; (void)out_size; (void)ws_size;
  const float* z     = (const float*)d_in[0];
  const float* x     = (const float*)d_in[1];
  const float* dimg  = (const float*)d_in[2];
  const float* dw_w  = (const float*)d_in[3];
  const float* dw_b  = (const float*)d_in[4];
  const float* pw_w  = (const float*)d_in[5];
  const float* pw_b  = (const float*)d_in[6];
  const float* bn_g  = (const float*)d_in[7];
  const float* bn_b  = (const float*)d_in[8];
  const float* bn_m  = (const float*)d_in[9];
  const float* bn_v  = (const float*)d_in[10];
  const float* inp_w = (const float*)d_in[11];
  const float* inp_b = (const float*)d_in[12];
  const float* q_w   = (const float*)d_in[13];
  const float* q_b   = (const float*)d_in[14];
  const float* k_w   = (const float*)d_in[15];
  const float* k_b   = (const float*)d_in[16];
  const float* v_w   = (const float*)d_in[17];
  const float* v_b   = (const float*)d_in[18];
  const float* op_w  = (const float*)d_in[19];
  const float* op_b  = (const float*)d_in[20];
  float* out = (float*)d_out;

  char* ws = (char*)d_ws;
  short* xt    = (short*)(ws + OB_XT);
  short* zt    = (short*)(ws + OB_ZT);
  short* dws   = (short*)(ws + OB_DWS);
  short* dt    = (short*)(ws + OB_DT);
  short* px_b  = (short*)(ws + OB_PX);
  short* corr  = (short*)(ws + OB_CORR);
  float* G     = (float*)(ws + OB_G);
  float* T1    = (float*)(ws + OB_T1);
  short* s_b   = (short*)(ws + OB_S);
  short* pxT   = (short*)(ws + OB_PXT);
  float* att   = (float*)(ws + OB_ATT);
  float* M2    = (float*)(ws + OB_M2);
  float* M3    = (float*)(ws + OB_M3);
  short* pw_wb = (short*)(ws + OB_PWW);
  short* inp_wb= (short*)(ws + OB_INPW);
  short* M3b   = (short*)(ws + OB_M3B);
  float* r     = (float*)(ws + OB_R);
  float* u     = (float*)(ws + OB_U);
  float* w2    = (float*)(ws + OB_W2);
  float* m2b   = (float*)(ws + OB_M2B);
  float* b3    = (float*)(ws + OB_B3);
  float* bns   = (float*)(ws + OB_BNS);
  float* bnh   = (float*)(ws + OB_BNH);

  const long long sNC = (long long)N_ * C_;
  const long long sNK = (long long)N_ * K_;
  const long long sNI = (long long)N_ * IN_;
  const long long sCC = (long long)C_ * C_;

  // --- prep: BN fold, weight casts, transpose-casts ---
  bncoef<<<1, 256, 0, stream>>>(pw_b, bn_g, bn_b, bn_m, bn_v, bns, bnh);
  castw<<<(IN_ * C_ + 255) / 256, 256, 0, stream>>>(pw_w, pw_wb, IN_ * C_);
  castw<<<(C_ * C_ + 255) / 256, 256, 0, stream>>>(inp_w, inp_wb, C_ * C_);
  tcast<<<dim3(N_ / 32, C_ / 32, B_), 256, 0, stream>>>(x, xt, C_, N_, sNC, sNC);
  tcast<<<dim3(K_ / 32, C_ / 32, B_), 256, 0, stream>>>(z, zt, C_, K_, (long long)C_ * K_,
                                                        (long long)C_ * K_);
  tcast<<<dim3(N_ / 32, C_ / 32, B_), 256, 0, stream>>>(dimg, dt, C_, N_, sNC, sNC);

  // --- corr[n,k] = sum_c xt[n,c] zt[k,c] : M=4096, BN=64, K=256, out bf16 ---
  mgemm<64, 1, 1><<<dim3(1, 32, B_), 256, 0, stream>>>(
      xt, C_, sNC, zt, C_, (long long)K_ * C_, corr, K_, sNK, C_,
      nullptr, nullptr, nullptr, nullptr, 0, 0, nullptr, 0, 0);

  // --- depthwise 3x3, output dws [n, 320] bf16 (vectorized, 8ch/thread) ---
  dwconv3<<<dim3(N_ * 40 / 256, B_), 256, 0, stream>>>(corr, dt, dw_w, dw_b, dws);

  // --- s[n,o] = relu(bn(sum_i dws[n,i] pw_w[o,i])) : out bf16 ---
  mgemm<128, 1, (1 | 4)><<<dim3(2, 32, B_), 256, 0, stream>>>(
      dws, IN_, sNI, pw_wb, IN_, 0, s_b, C_, sNC, IN_,
      bns, bnh, nullptr, nullptr, 0, 0, nullptr, 0, 0);

  // --- px[n,o] = sum_i s[n,i] inp_w[o,i] + inp_b : bf16 + transposed copy ---
  mgemm<128, 1, (1 | 2 | 32)><<<dim3(2, 32, B_), 256, 0, stream>>>(
      s_b, C_, sNC, inp_wb, C_, 0, px_b, C_, sNC, C_,
      inp_b, nullptr, nullptr, nullptr, 0, 0, pxT, N_, sNC);

  // --- r[b,c] = column sums of px ---
  hipMemsetAsync(r, 0, B_ * C_ * sizeof(float), stream);
  colsum<<<dim3(8, B_), 256, 0, stream>>>(px_b, r);

  // --- G = pxT @ pxT^T (K=4096, split-K=8, fp32 atomics) ---
  hipMemsetAsync(G, 0, (size_t)B_ * C_ * C_ * sizeof(float), stream);
  mgemm<128, 8, 64><<<dim3(2, 2, B_ * 8), 256, 0, stream>>>(
      pxT, N_, sNC, pxT, N_, sNC, G, C_, sCC, N_ / 8,
      nullptr, nullptr, nullptr, nullptr, 0, 0, nullptr, 0, 0);

  // --- rank-1 pieces ---
  uwker<<<B_, 256, 0, stream>>>(q_w, k_w, r, u, w2);

  // --- T1 = q_w @ G ; score = (1/16) T1 @ k_w^T (fp32 small GEMMs) ---
  gemm64<0, 0, 0><<<dim3(C_ / 64, C_ / 64, B_), 256, 0, stream>>>(
      q_w, C_, 0, G, C_, sCC, T1, C_, sCC, C_, 1.f);
  gemm64<0, 1, 8><<<dim3(C_ / 64, C_ / 64, B_), 256, 0, stream>>>(
      T1, C_, sCC, k_w, C_, 0, att, C_, sCC, C_, 0.0625f);

  fixsoftmax<<<dim3(C_, B_), 256, 0, stream>>>(att, u, w2, q_b, k_b);

  // --- M2 = att^T @ v_w ; M3 = op_w @ M2 ---
  gemm64<1, 0, 0><<<dim3(C_ / 64, C_ / 64, B_), 256, 0, stream>>>(
      att, C_, sCC, v_w, C_, 0, M2, C_, sCC, C_, 1.f);
  m2bker<<<B_, 256, 0, stream>>>(att, v_b, m2b);
  gemm64<0, 0, 0><<<dim3(C_ / 64, C_ / 64, B_), 256, 0, stream>>>(
      op_w, C_, 0, M2, C_, sCC, M3, C_, sCC, C_, 1.f);
  b3ker<<<B_, 256, 0, stream>>>(op_w, m2b, op_b, b3);
  castw<<<((int)(B_ * sCC) + 255) / 256, 256, 0, stream>>>(M3, M3b, B_ * sCC);

  // --- out[o,n] = sum_c M3[o,c] px[n,c] + b3[b,o] + s[n,o] : fp32, [b,c,h,w] ---
  mgemm<128, 1, (8 | 16)><<<dim3(32, 2, B_), 256, 0, stream>>>(
      M3b, C_, sCC, px_b, C_, sNC, out, N_, sNC, C_,
      nullptr, nullptr, b3, s_b, C_, sNC, nullptr, 0, 0);
}

// Round 3
// 853.304 us; speedup vs baseline: 1.3027x; 1.0312x over previous
//
#include <hip/hip_runtime.h>

static constexpr int B_ = 32, C_ = 256, K_ = 64, H_ = 64, W_ = 64;
static constexpr int N_ = H_ * W_;      // 4096
static constexpr int IN_ = C_ + K_;     // 320

// ---------------- bf16 helpers (raw short storage) ----------------
__device__ __forceinline__ short f2bs(float f) {
  unsigned u = __builtin_bit_cast(unsigned, f);
  u += 0x7fffu + ((u >> 16) & 1u);
  return (short)(u >> 16);
}
__device__ __forceinline__ float bs2f(short s) {
  unsigned u = ((unsigned)(unsigned short)s) << 16;
  return __builtin_bit_cast(float, u);
}

typedef __attribute__((ext_vector_type(8))) short s8v;
typedef __attribute__((ext_vector_type(4))) short s4v;
typedef __attribute__((ext_vector_type(4))) float f4v;

// ---------------- workspace layout (bytes) ----------------
static constexpr long long OB_XT   = 0;
static constexpr long long OB_ZT   = 67108864LL;
static constexpr long long OB_DWS  = 0;
static constexpr long long OB_DT   = 83886080LL;
static constexpr long long OB_PX   = 83886080LL;
static constexpr long long OB_CORR = 150994944LL;
static constexpr long long OB_G    = 150994944LL;
static constexpr long long OB_GB2  = 159383552LL;   // G hi/lo bf16 [b][f][512] = 8MB
static constexpr long long OB_S    = 167772160LL;
static constexpr long long OB_PXT  = 234881024LL;
static constexpr long long OB_ATT  = 301989888LL;
static constexpr long long OB_M2   = OB_ATT + 8388608LL;   // bf16 scratch (M2 main out)
static constexpr long long OB_M3   = OB_M2 + 8388608LL;    // unused
static constexpr long long OB_MISC = OB_M3 + 8388608LL;
static constexpr long long OB_PWW  = OB_MISC;
static constexpr long long OB_INPW = OB_PWW + 262144LL;
static constexpr long long OB_M3B  = OB_INPW + 262144LL;   // 4MB bf16
static constexpr long long OB_R    = OB_M3B + 4194304LL;
static constexpr long long OB_U    = OB_R + 32768LL;
static constexpr long long OB_W2   = OB_U + 32768LL;
static constexpr long long OB_M2B  = OB_W2 + 32768LL;
static constexpr long long OB_B3   = OB_M2B + 32768LL;
static constexpr long long OB_BNS  = OB_B3 + 32768LL;
static constexpr long long OB_BNH  = OB_BNS + 2048LL;
static constexpr long long OB_QW2  = OB_BNH + 2048LL;      // q_w dup [256][512] bf16
static constexpr long long OB_KWB  = OB_QW2 + 262144LL;
static constexpr long long OB_VWB  = OB_KWB + 131072LL;    // (dead, kept for layout)
static constexpr long long OB_OPWB = OB_VWB + 131072LL;
static constexpr long long OB_T1B  = OB_OPWB + 131072LL;   // 4MB bf16
static constexpr long long OB_ATTT = OB_T1B + 4194304LL;   // 4MB bf16
static constexpr long long OB_M2T  = OB_ATTT + 4194304LL;  // 4MB bf16
static constexpr long long OB_VWT  = OB_M2T + 4194304LL;   // v_w^T bf16 [f][c]
// end ~345.4MB (< 378MB verified available)

// ---------------- async global->LDS ----------------
__device__ __forceinline__ void gload16(const void* g, void* l) {
  __builtin_amdgcn_global_load_lds((const __attribute__((address_space(1))) void*)g,
                                   (__attribute__((address_space(3))) void*)l, 16, 0, 0);
}

// ===========================================================================
// MFMA bf16 GEMM: D[m,n] = sum_k A[m,k] * Bt[n,k]
// EPI bits: 1=out bf16, 2=+biasc[n], 4=relu(v*biasc[n]+shf[n]), 8=+biasr[bz*256+m],
//           16=+resT[n*ldrt+m] (bf16), 32=also write bf16 outT[n*ldt+m], 64=atomicAdd f32
// ===========================================================================
template <int BN, int SPLIT, int EPI>
__global__ __launch_bounds__(256) void mgemm(
    const short* __restrict__ A, int lda, long long sA,
    const short* __restrict__ Bt, int ldb, long long sB,
    void* __restrict__ Cv, int ldc, long long sC,
    int Kd,
    const float* __restrict__ biasc, const float* __restrict__ shf,
    const float* __restrict__ biasr,
    const short* __restrict__ resT, int ldrt, long long sRT,
    short* __restrict__ outT, int ldt, long long sT)
{
  constexpr int JT = BN / 32;
  __shared__ short As[128 * 32];
  __shared__ short Bs[BN * 32];

  const int t = threadIdx.x;
  const int wv = t >> 6;
  const int lane = t & 63, quad = lane >> 4, lr = lane & 15;
  const int wm = wv >> 1, wn = wv & 1;
  const int m_off = wm * 64, n_off = wn * (BN / 2);

  const int n0 = blockIdx.x * BN;
  const int m0 = blockIdx.y * 128;
  const int bz = (SPLIT == 1) ? blockIdx.z : (blockIdx.z / SPLIT);
  const int sp = (SPLIT == 1) ? 0 : (blockIdx.z % SPLIT);
  const int koff = sp * Kd;

  A += (long long)bz * sA;
  Bt += (long long)bz * sB;

  const int arow = t >> 2;
  const int acol = (t & 3) << 3;

  f4v acc[4][JT];
#pragma unroll
  for (int i = 0; i < 4; ++i)
#pragma unroll
    for (int j = 0; j < JT; ++j) acc[i][j] = (f4v)0.f;

  for (int k0 = 0; k0 < Kd; k0 += 32) {
#pragma unroll
    for (int rr = 0; rr < 2; ++rr) {
      const short* gp = A + (long long)(m0 + rr * 64 + arow) * lda + koff + k0 + acol;
      gload16(gp, (char*)As + rr * 4096 + wv * 1024);
    }
#pragma unroll
    for (int rr = 0; rr < BN / 64; ++rr) {
      const short* gp = Bt + (long long)(n0 + rr * 64 + arow) * ldb + koff + k0 + acol;
      gload16(gp, (char*)Bs + rr * 4096 + wv * 1024);
    }
    __syncthreads();

    s8v af[4], bfv[JT];
#pragma unroll
    for (int i = 0; i < 4; ++i)
      af[i] = *(const s8v*)&As[(m_off + i * 16 + lr) * 32 + quad * 8];
#pragma unroll
    for (int j = 0; j < JT; ++j)
      bfv[j] = *(const s8v*)&Bs[(n_off + j * 16 + lr) * 32 + quad * 8];
#pragma unroll
    for (int i = 0; i < 4; ++i)
#pragma unroll
      for (int j = 0; j < JT; ++j)
        acc[i][j] = __builtin_amdgcn_mfma_f32_16x16x32_bf16(af[i], bfv[j], acc[i][j], 0, 0, 0);
    __syncthreads();
  }

  float* Cf = (float*)Cv;
  short* Cb = (short*)Cv;
  if (EPI & 1) Cb += (long long)bz * sC; else Cf += (long long)bz * sC;
  if (EPI & 16) resT += (long long)bz * sRT;
  if (EPI & 32) outT += (long long)bz * sT;

#pragma unroll
  for (int i = 0; i < 4; ++i) {
    const int mb = m0 + m_off + i * 16 + quad * 4;
#pragma unroll
    for (int j = 0; j < JT; ++j) {
      const int n = n0 + n_off + j * 16 + lr;
      float vr[4];
#pragma unroll
      for (int r = 0; r < 4; ++r) {
        float v = acc[i][j][r];
        if (EPI & 2) v += biasc[n];
        if (EPI & 4) v = fmaxf(fmaf(v, biasc[n], shf[n]), 0.f);
        if (EPI & 8) v += biasr[bz * 256 + mb + r];
        vr[r] = v;
      }
      if (EPI & 16) {
        s4v rv = *(const s4v*)(resT + (long long)n * ldrt + mb);
#pragma unroll
        for (int r = 0; r < 4; ++r) vr[r] += bs2f(rv[r]);
      }
      if (EPI & 32) {
        s4v tv;
#pragma unroll
        for (int r = 0; r < 4; ++r) tv[r] = f2bs(vr[r]);
        *(s4v*)(outT + (long long)n * ldt + mb) = tv;
      }
#pragma unroll
      for (int r = 0; r < 4; ++r) {
        if (EPI & 64) atomicAdd(&Cf[(long long)(mb + r) * ldc + n], vr[r]);
        else if (EPI & 1) Cb[(long long)(mb + r) * ldc + n] = f2bs(vr[r]);
        else Cf[(long long)(mb + r) * ldc + n] = vr[r];
      }
    }
  }
}

// ---------------- transpose-cast: in fp32 [R? no: [*, Cc]] -> out bf16 [Cc, R] ----
__global__ __launch_bounds__(256) void tcast(const float* __restrict__ in,
                                             short* __restrict__ out,
                                             int R, int Cc, long long sIn, long long sOut)
{
  __shared__ float tile[32][33];
  const int b = blockIdx.z;
  const int r0 = blockIdx.y * 32, c0 = blockIdx.x * 32;
  in += (long long)b * sIn;
  out += (long long)b * sOut;
  const int tx = threadIdx.x & 31, ty = threadIdx.x >> 5;
#pragma unroll
  for (int i = 0; i < 32; i += 8)
    tile[ty + i][tx] = in[(long long)(r0 + ty + i) * Cc + c0 + tx];
  __syncthreads();
#pragma unroll
  for (int i = 0; i < 32; i += 8)
    out[(long long)(c0 + ty + i) * R + r0 + tx] = f2bs(tile[tx][ty + i]);
}

// ---------------- flat fp32 -> bf16 cast ----------------
__global__ void castw(const float* __restrict__ in, short* __restrict__ out, long long n)
{
  long long i = (long long)blockIdx.x * 256 + threadIdx.x;
  if (i < n) out[i] = f2bs(in[i]);
}

// ---------------- cast 2 weight matrices (65536 elems each) ----------------
__global__ void castw2(const float* __restrict__ a, const float* __restrict__ b,
                       short* __restrict__ oa, short* __restrict__ ob)
{
  const int i = blockIdx.x * 256 + threadIdx.x;   // < 2*65536
  const int sel = i >> 16, off = i & 65535;
  const float* src = sel == 0 ? a : b;
  short* dst = sel == 0 ? oa : ob;
  dst[off] = f2bs(src[off]);
}

// ---------------- q_w -> bf16 duplicated along K ----------------
__global__ void qdup(const float* __restrict__ q, short* __restrict__ o)
{
  const int i = blockIdx.x * 256 + threadIdx.x;   // < 65536
  const short v = f2bs(q[i]);
  const int c = i >> 8, e = i & 255;
  o[c * 512 + e] = v;
  o[c * 512 + 256 + e] = v;
}

// ---------------- G fp32 -> hi/lo bf16 pair ----------------
__global__ void ghilo(const float* __restrict__ G, short* __restrict__ g2)
{
  const long long i = (long long)blockIdx.x * 256 + threadIdx.x;  // < 32*65536
  const float g = G[i];
  const short h = f2bs(g);
  const short l = f2bs(g - bs2f(h));
  const long long row = i >> 8;
  const int e = (int)(i & 255);
  g2[row * 512 + e] = h;
  g2[row * 512 + 256 + e] = l;
}

// ===========================================================================
// depthwise 3x3 over concat([corr(64), d(256)]), [N,ch] layout.
// Each thread: 8 channels x 4 vertical pixels (strip).
// ===========================================================================
__global__ __launch_bounds__(256) void dwconv4(const short* __restrict__ corr,
                                               const short* __restrict__ dt,
                                               const float* __restrict__ wgt,
                                               const float* __restrict__ bias,
                                               short* __restrict__ outp)
{
  __shared__ __align__(16) float wl[9 * IN_];
  __shared__ __align__(16) float bl[IN_];
  const int tid = threadIdx.x;
  for (int i = tid; i < 9 * IN_; i += 256) {
    const int ch = i / 9, tap = i % 9;
    wl[tap * IN_ + ch] = wgt[i];
  }
  for (int i = tid; i < IN_; i += 256) bl[i] = bias[i];
  __syncthreads();

  const int g = blockIdx.x * 256 + tid;   // 0..40959
  const int b = blockIdx.y;
  const int cg = g % 40;
  const int rest = g / 40;                // 0..1023
  const int x = rest & 63;
  const int y0 = (rest >> 6) << 2;        // 0,4,...,60
  const int ch0 = cg * 8;

  const short* base;
  int ldch, c0;
  if (cg < 8) { base = corr + (long long)b * N_ * K_; ldch = K_; c0 = ch0; }
  else        { base = dt   + (long long)b * N_ * C_; ldch = C_; c0 = ch0 - K_; }

  float acc[4][8];
  {
    float4 bv0 = *(const float4*)&bl[ch0];
    float4 bv1 = *(const float4*)&bl[ch0 + 4];
#pragma unroll
    for (int p = 0; p < 4; ++p) {
      acc[p][0] = bv0.x; acc[p][1] = bv0.y; acc[p][2] = bv0.z; acc[p][3] = bv0.w;
      acc[p][4] = bv1.x; acc[p][5] = bv1.y; acc[p][6] = bv1.z; acc[p][7] = bv1.w;
    }
  }

#pragma unroll
  for (int dx = -1; dx <= 1; ++dx) {
    const int xx = x + dx;
    if (xx < 0 || xx >= W_) continue;

    float wv[3][8];
#pragma unroll
    for (int dy1 = 0; dy1 < 3; ++dy1) {
      float4 wa = *(const float4*)&wl[(dy1 * 3 + (dx + 1)) * IN_ + ch0];
      float4 wb = *(const float4*)&wl[(dy1 * 3 + (dx + 1)) * IN_ + ch0 + 4];
      wv[dy1][0] = wa.x; wv[dy1][1] = wa.y; wv[dy1][2] = wa.z; wv[dy1][3] = wa.w;
      wv[dy1][4] = wb.x; wv[dy1][5] = wb.y; wv[dy1][6] = wb.z; wv[dy1][7] = wb.w;
    }

    s8v v[6];
#pragma unroll
    for (int ri = 0; ri < 6; ++ri) {
      const int yy = y0 - 1 + ri;
      if (yy >= 0 && yy < H_)
        v[ri] = *(const s8v*)(base + (long long)(yy * W_ + xx) * ldch + c0);
      else
        v[ri] = (s8v)0;
    }

#pragma unroll
    for (int ri = 0; ri < 6; ++ri) {
      float f[8];
#pragma unroll
      for (int j = 0; j < 8; ++j) f[j] = bs2f(v[ri][j]);
#pragma unroll
      for (int dy1 = 0; dy1 < 3; ++dy1) {
        const int p = ri - dy1;
        if (p < 0 || p > 3) continue;
#pragma unroll
        for (int j = 0; j < 8; ++j)
          acc[p][j] = fmaf(wv[dy1][j], f[j], acc[p][j]);
      }
    }
  }

#pragma unroll
  for (int p = 0; p < 4; ++p) {
    s8v o;
#pragma unroll
    for (int j = 0; j < 8; ++j) o[j] = f2bs(acc[p][j]);
    *(s8v*)(outp + ((long long)b * N_ + (y0 + p) * W_ + x) * IN_ + ch0) = o;
  }
}

// ---------------- column sums of px_b [N, C] -> r[b, c] (atomic) ----------------
__global__ void colsum(const short* __restrict__ px, float* __restrict__ r)
{
  const int b = blockIdx.y, c = threadIdx.x, chunk = blockIdx.x;
  const short* p = px + (long long)b * N_ * C_ + (long long)chunk * 512 * C_;
  float s = 0.f;
  for (int n = 0; n < 512; ++n) s += bs2f(p[(long long)n * C_ + c]);
  atomicAdd(&r[b * C_ + c], s);
}

// ---------------- small fused kernels ----------------
__global__ void bncoef(const float* __restrict__ pwb, const float* __restrict__ g,
                       const float* __restrict__ bt, const float* __restrict__ mn,
                       const float* __restrict__ vr, float* __restrict__ scl,
                       float* __restrict__ shf)
{
  const int c = threadIdx.x;
  const float inv = rsqrtf(vr[c] + 1e-5f);
  const float sc = g[c] * inv;
  scl[c] = sc;
  shf[c] = (pwb[c] - mn[c]) * sc + bt[c];
}

__global__ void uwker(const float* __restrict__ qw, const float* __restrict__ kw,
                      const float* __restrict__ r, float* __restrict__ u,
                      float* __restrict__ w)
{
  const int b = blockIdx.x, c = threadIdx.x;
  __shared__ float rl[256];
  rl[c] = r[b * C_ + c];
  __syncthreads();
  float su = 0.f, sw = 0.f;
  for (int f = 0; f < C_; ++f) {
    const float rv = rl[f];
    su = fmaf(qw[c * C_ + f], rv, su);
    sw = fmaf(kw[c * C_ + f], rv, sw);
  }
  u[b * C_ + c] = su;
  w[b * C_ + c] = sw;
}

// att buffer holds UNscaled logits (T1 @ k_w^T); scale by 1/16 here.
__global__ void fixsoftmax(float* __restrict__ att, const float* __restrict__ u,
                           const float* __restrict__ w, const float* __restrict__ qb,
                           const float* __restrict__ kb)
{
  const int c = blockIdx.x, b = blockIdx.y, d = threadIdx.x;
  const long long base = ((long long)b * C_ + c) * (long long)C_;
  const float qbc = qb[c];
  float val = 0.0625f * (att[base + d] + u[b * C_ + c] * kb[d] + qbc * w[b * C_ + d] +
                         (float)N_ * qbc * kb[d]);
  __shared__ float red[256];
  red[d] = val;
  __syncthreads();
  for (int k = 128; k > 0; k >>= 1) {
    if (d < k) red[d] = fmaxf(red[d], red[d + k]);
    __syncthreads();
  }
  const float mx = red[0];
  __syncthreads();
  const float e = expf(val - mx);
  red[d] = e;
  __syncthreads();
  for (int k = 128; k > 0; k >>= 1) {
    if (d < k) red[d] += red[d + k];
    __syncthreads();
  }
  att[base + d] = e / red[0];
}

__global__ void m2bker(const float* __restrict__ att, const float* __restrict__ vb,
                       float* __restrict__ m2b)
{
  const int b = blockIdx.x, d = threadIdx.x;
  const float* a = att + (long long)b * C_ * C_;
  float s = 0.f;
  for (int c = 0; c < C_; ++c) s = fmaf(a[c * C_ + d], vb[c], s);
  m2b[b * C_ + d] = s;
}

__global__ void b3ker(const float* __restrict__ opw, const float* __restrict__ m2b,
                      const float* __restrict__ opb, float* __restrict__ b3)
{
  const int b = blockIdx.x, o = threadIdx.x;
  __shared__ float m[256];
  m[o] = m2b[b * C_ + o];
  __syncthreads();
  float s = opb[o];
  for (int d = 0; d < C_; ++d) s = fmaf(opw[o * C_ + d], m[d], s);
  b3[b * C_ + o] = s;
}

// ===========================================================================
extern "C" void kernel_launch(void* const* d_in, const int* in_sizes, int n_in,
                              void* d_out, int out_size, void* d_ws, size_t ws_size,
                              hipStream_t stream)
{
  (void)in_sizes; (void)n_in; (void)out_size; (void)ws_size;
  const float* z     = (const float*)d_in[0];
  const float* x     = (const float*)d_in[1];
  const float* dimg  = (const float*)d_in[2];
  const float* dw_w  = (const float*)d_in[3];
  const float* dw_b  = (const float*)d_in[4];
  const float* pw_w  = (const float*)d_in[5];
  const float* pw_b  = (const float*)d_in[6];
  const float* bn_g  = (const float*)d_in[7];
  const float* bn_b  = (const float*)d_in[8];
  const float* bn_m  = (const float*)d_in[9];
  const float* bn_v  = (const float*)d_in[10];
  const float* inp_w = (const float*)d_in[11];
  const float* inp_b = (const float*)d_in[12];
  const float* q_w   = (const float*)d_in[13];
  const float* q_b   = (const float*)d_in[14];
  const float* k_w   = (const float*)d_in[15];
  const float* k_b   = (const float*)d_in[16];
  const float* v_w   = (const float*)d_in[17];
  const float* v_b   = (const float*)d_in[18];
  const float* op_w  = (const float*)d_in[19];
  const float* op_b  = (const float*)d_in[20];
  float* out = (float*)d_out;

  char* ws = (char*)d_ws;
  short* xt    = (short*)(ws + OB_XT);
  short* zt    = (short*)(ws + OB_ZT);
  short* dws   = (short*)(ws + OB_DWS);
  short* dt    = (short*)(ws + OB_DT);
  short* px_b  = (short*)(ws + OB_PX);
  short* corr  = (short*)(ws + OB_CORR);
  float* G     = (float*)(ws + OB_G);
  short* Gb2   = (short*)(ws + OB_GB2);
  short* s_b   = (short*)(ws + OB_S);
  short* pxT   = (short*)(ws + OB_PXT);
  float* att   = (float*)(ws + OB_ATT);
  short* M2scr = (short*)(ws + OB_M2);
  short* pw_wb = (short*)(ws + OB_PWW);
  short* inp_wb= (short*)(ws + OB_INPW);
  short* M3b   = (short*)(ws + OB_M3B);
  float* r     = (float*)(ws + OB_R);
  float* u     = (float*)(ws + OB_U);
  float* w2    = (float*)(ws + OB_W2);
  float* m2b   = (float*)(ws + OB_M2B);
  float* b3    = (float*)(ws + OB_B3);
  float* bns   = (float*)(ws + OB_BNS);
  float* bnh   = (float*)(ws + OB_BNH);
  short* q_wb2 = (short*)(ws + OB_QW2);
  short* k_wb  = (short*)(ws + OB_KWB);
  short* op_wb = (short*)(ws + OB_OPWB);
  short* T1b   = (short*)(ws + OB_T1B);
  short* attT  = (short*)(ws + OB_ATTT);
  short* M2T   = (short*)(ws + OB_M2T);
  short* v_wT  = (short*)(ws + OB_VWT);

  const long long sNC = (long long)N_ * C_;
  const long long sNK = (long long)N_ * K_;
  const long long sNI = (long long)N_ * IN_;
  const long long sCC = (long long)C_ * C_;

  // --- prep: BN fold, weight casts, transpose-casts ---
  bncoef<<<1, 256, 0, stream>>>(pw_b, bn_g, bn_b, bn_m, bn_v, bns, bnh);
  castw<<<(IN_ * C_ + 255) / 256, 256, 0, stream>>>(pw_w, pw_wb, IN_ * C_);
  castw<<<(C_ * C_ + 255) / 256, 256, 0, stream>>>(inp_w, inp_wb, C_ * C_);
  qdup<<<256, 256, 0, stream>>>(q_w, q_wb2);
  castw2<<<512, 256, 0, stream>>>(k_w, op_w, k_wb, op_wb);
  tcast<<<dim3(8, 8, 1), 256, 0, stream>>>(v_w, v_wT, C_, C_, 0, 0);   // v_wT[f][c] = v_w[c][f]
  tcast<<<dim3(N_ / 32, C_ / 32, B_), 256, 0, stream>>>(x, xt, C_, N_, sNC, sNC);
  tcast<<<dim3(K_ / 32, C_ / 32, B_), 256, 0, stream>>>(z, zt, C_, K_, (long long)C_ * K_,
                                                        (long long)C_ * K_);
  tcast<<<dim3(N_ / 32, C_ / 32, B_), 256, 0, stream>>>(dimg, dt, C_, N_, sNC, sNC);

  // --- corr[n,k] = sum_c xt[n,c] zt[k,c] ---
  mgemm<64, 1, 1><<<dim3(1, 32, B_), 256, 0, stream>>>(
      xt, C_, sNC, zt, C_, (long long)K_ * C_, corr, K_, sNK, C_,
      nullptr, nullptr, nullptr, nullptr, 0, 0, nullptr, 0, 0);

  // --- depthwise 3x3, output dws [n, 320] bf16 (4-pixel strip per thread) ---
  dwconv4<<<dim3(160, B_), 256, 0, stream>>>(corr, dt, dw_w, dw_b, dws);

  // --- s[n,o] = relu(bn(sum_i dws[n,i] pw_w[o,i])) ---
  mgemm<128, 1, (1 | 4)><<<dim3(2, 32, B_), 256, 0, stream>>>(
      dws, IN_, sNI, pw_wb, IN_, 0, s_b, C_, sNC, IN_,
      bns, bnh, nullptr, nullptr, 0, 0, nullptr, 0, 0);

  // --- px[n,o] = sum_i s[n,i] inp_w[o,i] + inp_b : bf16 + transposed copy ---
  mgemm<128, 1, (1 | 2 | 32)><<<dim3(2, 32, B_), 256, 0, stream>>>(
      s_b, C_, sNC, inp_wb, C_, 0, px_b, C_, sNC, C_,
      inp_b, nullptr, nullptr, nullptr, 0, 0, pxT, N_, sNC);

  // --- r[b,c] = column sums of px ---
  hipMemsetAsync(r, 0, B_ * C_ * sizeof(float), stream);
  colsum<<<dim3(8, B_), 256, 0, stream>>>(px_b, r);

  // --- G = pxT @ pxT^T (K=4096, split-K=8, fp32 atomics) ---
  hipMemsetAsync(G, 0, (size_t)B_ * C_ * C_ * sizeof(float), stream);
  mgemm<128, 8, 64><<<dim3(2, 2, B_ * 8), 256, 0, stream>>>(
      pxT, N_, sNC, pxT, N_, sNC, G, C_, sCC, N_ / 8,
      nullptr, nullptr, nullptr, nullptr, 0, 0, nullptr, 0, 0);

  // --- G -> hi/lo bf16 pair ---
  ghilo<<<8192, 256, 0, stream>>>(G, Gb2);

  // --- rank-1 pieces ---
  uwker<<<B_, 256, 0, stream>>>(q_w, k_w, r, u, w2);

  // --- T1[c,g] = sum_f q_w[c,f] G[f,g] : MFMA K=512 (hi+lo), out bf16 ---
  mgemm<128, 1, 1><<<dim3(2, 2, B_), 256, 0, stream>>>(
      q_wb2, 512, 0, Gb2, 512, 256LL * 512, T1b, C_, sCC, 512,
      nullptr, nullptr, nullptr, nullptr, 0, 0, nullptr, 0, 0);

  // --- logits[c,d] = sum_g T1[c,g] k_w[d,g] (unscaled) : fp32 out ---
  mgemm<128, 1, 0><<<dim3(2, 2, B_), 256, 0, stream>>>(
      T1b, C_, sCC, k_wb, C_, 0, att, C_, sCC, C_,
      nullptr, nullptr, nullptr, nullptr, 0, 0, nullptr, 0, 0);

  fixsoftmax<<<dim3(C_, B_), 256, 0, stream>>>(att, u, w2, q_b, k_b);

  // --- attT[d][c] = att[c][d] bf16 ---
  tcast<<<dim3(8, 8, B_), 256, 0, stream>>>(att, attT, C_, C_, sCC, sCC);

  // --- M2[d][f] = sum_c att[c,d] v_w[c,f] = attT @ v_wT^T ; write M2T[f][d] bf16 ---
  mgemm<128, 1, (1 | 32)><<<dim3(2, 2, B_), 256, 0, stream>>>(
      attT, C_, sCC, v_wT, C_, 0, M2scr, C_, sCC, C_,
      nullptr, nullptr, nullptr, nullptr, 0, 0, M2T, C_, sCC);

  // --- M3[o][f] = sum_d op_w[o,d] M2[d,f] : bf16 out ---
  mgemm<128, 1, 1><<<dim3(2, 2, B_), 256, 0, stream>>>(
      op_wb, C_, 0, M2T, C_, sCC, M3b, C_, sCC, C_,
      nullptr, nullptr, nullptr, nullptr, 0, 0, nullptr, 0, 0);

  m2bker<<<B_, 256, 0, stream>>>(att, v_b, m2b);
  b3ker<<<B_, 256, 0, stream>>>(op_w, m2b, op_b, b3);

  // --- out[o,n] = sum_f M3[o,f] px[n,f] + b3[b,o] + s[n,o] : fp32, [b,c,h,w] ---
  mgemm<128, 1, (8 | 16)><<<dim3(32, 2, B_), 256, 0, stream>>>(
      M3b, C_, sCC, px_b, C_, sNC, out, N_, sNC, C_,
      nullptr, nullptr, b3, s_b, C_, sNC, nullptr, 0, 0);
}

// Round 5
// 835.046 us; speedup vs baseline: 1.3312x; 1.0219x over previous
//
#include <hip/hip_runtime.h>

static constexpr int B_ = 32, C_ = 256, K_ = 64, H_ = 64, W_ = 64;
static constexpr int N_ = H_ * W_;      // 4096
static constexpr int IN_ = C_ + K_;     // 320

// ---------------- bf16 helpers (raw short storage) ----------------
__device__ __forceinline__ short f2bs(float f) {
  unsigned u = __builtin_bit_cast(unsigned, f);
  u += 0x7fffu + ((u >> 16) & 1u);
  return (short)(u >> 16);
}
__device__ __forceinline__ float bs2f(short s) {
  unsigned u = ((unsigned)(unsigned short)s) << 16;
  return __builtin_bit_cast(float, u);
}

typedef __attribute__((ext_vector_type(8))) short s8v;
typedef __attribute__((ext_vector_type(4))) short s4v;
typedef __attribute__((ext_vector_type(4))) float f4v;

// ---------------- workspace layout (bytes) ----------------
static constexpr long long OB_XT   = 0;
static constexpr long long OB_ZT   = 67108864LL;
static constexpr long long OB_DWS  = 0;
static constexpr long long OB_DT   = 83886080LL;
static constexpr long long OB_PX   = 83886080LL;
static constexpr long long OB_CORR = 150994944LL;
static constexpr long long OB_G    = 150994944LL;
static constexpr long long OB_GB2  = 159383552LL;   // G hi/lo bf16 [b][f][512] = 8MB
static constexpr long long OB_S    = 167772160LL;
static constexpr long long OB_PXT  = 234881024LL;
static constexpr long long OB_ATT  = 301989888LL;
static constexpr long long OB_M2   = OB_ATT + 8388608LL;   // bf16 scratch (M2 main out)
static constexpr long long OB_M3   = OB_M2 + 8388608LL;    // unused
static constexpr long long OB_MISC = OB_M3 + 8388608LL;
static constexpr long long OB_PWW  = OB_MISC;
static constexpr long long OB_INPW = OB_PWW + 262144LL;
static constexpr long long OB_M3B  = OB_INPW + 262144LL;   // 4MB bf16
static constexpr long long OB_R    = OB_M3B + 4194304LL;
static constexpr long long OB_U    = OB_R + 32768LL;
static constexpr long long OB_W2   = OB_U + 32768LL;
static constexpr long long OB_M2B  = OB_W2 + 32768LL;
static constexpr long long OB_B3   = OB_M2B + 32768LL;
static constexpr long long OB_BNS  = OB_B3 + 32768LL;
static constexpr long long OB_BNH  = OB_BNS + 2048LL;
static constexpr long long OB_QW2  = OB_BNH + 2048LL;      // q_w dup [256][512] bf16
static constexpr long long OB_KWB  = OB_QW2 + 262144LL;
static constexpr long long OB_VWB  = OB_KWB + 131072LL;    // (dead, kept for layout)
static constexpr long long OB_OPWB = OB_VWB + 131072LL;
static constexpr long long OB_T1B  = OB_OPWB + 131072LL;   // 4MB bf16
static constexpr long long OB_ATTT = OB_T1B + 4194304LL;   // 4MB bf16
static constexpr long long OB_M2T  = OB_ATTT + 4194304LL;  // 4MB bf16
static constexpr long long OB_VWT  = OB_M2T + 4194304LL;   // v_w^T bf16 [f][c]
// end ~345.4MB (< 378MB verified available)

// ---------------- async global->LDS ----------------
__device__ __forceinline__ void gload16(const void* g, void* l) {
  __builtin_amdgcn_global_load_lds((const __attribute__((address_space(1))) void*)g,
                                   (__attribute__((address_space(3))) void*)l, 16, 0, 0);
}

// ===========================================================================
// MFMA bf16 GEMM: D[m,n] = sum_k A[m,k] * Bt[n,k]
// EPI bits: 1=out bf16, 2=+biasc[n], 4=relu(v*biasc[n]+shf[n]), 8=+biasr[bz*256+m],
//           16=+resT[n*ldrt+m] (bf16), 32=also write bf16 outT[n*ldt+m], 64=atomicAdd f32
// ===========================================================================
template <int BN, int SPLIT, int EPI>
__global__ __launch_bounds__(256) void mgemm(
    const short* __restrict__ A, int lda, long long sA,
    const short* __restrict__ Bt, int ldb, long long sB,
    void* __restrict__ Cv, int ldc, long long sC,
    int Kd,
    const float* __restrict__ biasc, const float* __restrict__ shf,
    const float* __restrict__ biasr,
    const short* __restrict__ resT, int ldrt, long long sRT,
    short* __restrict__ outT, int ldt, long long sT)
{
  constexpr int JT = BN / 32;
  __shared__ short As[128 * 32];
  __shared__ short Bs[BN * 32];

  const int t = threadIdx.x;
  const int wv = t >> 6;
  const int lane = t & 63, quad = lane >> 4, lr = lane & 15;
  const int wm = wv >> 1, wn = wv & 1;
  const int m_off = wm * 64, n_off = wn * (BN / 2);

  const int n0 = blockIdx.x * BN;
  const int m0 = blockIdx.y * 128;
  const int bz = (SPLIT == 1) ? blockIdx.z : (blockIdx.z / SPLIT);
  const int sp = (SPLIT == 1) ? 0 : (blockIdx.z % SPLIT);
  const int koff = sp * Kd;

  A += (long long)bz * sA;
  Bt += (long long)bz * sB;

  const int arow = t >> 2;
  const int acol = (t & 3) << 3;

  f4v acc[4][JT];
#pragma unroll
  for (int i = 0; i < 4; ++i)
#pragma unroll
    for (int j = 0; j < JT; ++j) acc[i][j] = (f4v)0.f;

  for (int k0 = 0; k0 < Kd; k0 += 32) {
#pragma unroll
    for (int rr = 0; rr < 2; ++rr) {
      const short* gp = A + (long long)(m0 + rr * 64 + arow) * lda + koff + k0 + acol;
      gload16(gp, (char*)As + rr * 4096 + wv * 1024);
    }
#pragma unroll
    for (int rr = 0; rr < BN / 64; ++rr) {
      const short* gp = Bt + (long long)(n0 + rr * 64 + arow) * ldb + koff + k0 + acol;
      gload16(gp, (char*)Bs + rr * 4096 + wv * 1024);
    }
    __syncthreads();

    s8v af[4], bfv[JT];
#pragma unroll
    for (int i = 0; i < 4; ++i)
      af[i] = *(const s8v*)&As[(m_off + i * 16 + lr) * 32 + quad * 8];
#pragma unroll
    for (int j = 0; j < JT; ++j)
      bfv[j] = *(const s8v*)&Bs[(n_off + j * 16 + lr) * 32 + quad * 8];
#pragma unroll
    for (int i = 0; i < 4; ++i)
#pragma unroll
      for (int j = 0; j < JT; ++j)
        acc[i][j] = __builtin_amdgcn_mfma_f32_16x16x32_bf16(af[i], bfv[j], acc[i][j], 0, 0, 0);
    __syncthreads();
  }

  float* Cf = (float*)Cv;
  short* Cb = (short*)Cv;
  if (EPI & 1) Cb += (long long)bz * sC; else Cf += (long long)bz * sC;
  if (EPI & 16) resT += (long long)bz * sRT;
  if (EPI & 32) outT += (long long)bz * sT;

#pragma unroll
  for (int i = 0; i < 4; ++i) {
    const int mb = m0 + m_off + i * 16 + quad * 4;
#pragma unroll
    for (int j = 0; j < JT; ++j) {
      const int n = n0 + n_off + j * 16 + lr;
      float vr[4];
#pragma unroll
      for (int r = 0; r < 4; ++r) {
        float v = acc[i][j][r];
        if (EPI & 2) v += biasc[n];
        if (EPI & 4) v = fmaxf(fmaf(v, biasc[n], shf[n]), 0.f);
        if (EPI & 8) v += biasr[bz * 256 + mb + r];
        vr[r] = v;
      }
      if (EPI & 16) {
        s4v rv = *(const s4v*)(resT + (long long)n * ldrt + mb);
#pragma unroll
        for (int r = 0; r < 4; ++r) vr[r] += bs2f(rv[r]);
      }
      if (EPI & 32) {
        s4v tv;
#pragma unroll
        for (int r = 0; r < 4; ++r) tv[r] = f2bs(vr[r]);
        *(s4v*)(outT + (long long)n * ldt + mb) = tv;
      }
#pragma unroll
      for (int r = 0; r < 4; ++r) {
        if (EPI & 64) atomicAdd(&Cf[(long long)(mb + r) * ldc + n], vr[r]);
        else if (EPI & 1) Cb[(long long)(mb + r) * ldc + n] = f2bs(vr[r]);
        else Cf[(long long)(mb + r) * ldc + n] = vr[r];
      }
    }
  }
}

// ===========================================================================
// vectorized transpose-cast: in fp32 [R rows, Cc cols] -> out bf16 [Cc, R]
// 64x64 tile: float4 loads (16B/lane), s8v stores (16B/lane).
// grid (Cc/64, R/64, batch)
// ===========================================================================
__global__ __launch_bounds__(256) void tcast8(const float* __restrict__ in,
                                              short* __restrict__ out,
                                              int R, int Cc, long long sIn, long long sOut)
{
  __shared__ __align__(16) float tile[64][68];
  const int b = blockIdx.z;
  const int c0 = blockIdx.x * 64, r0 = blockIdx.y * 64;
  in += (long long)b * sIn;
  out += (long long)b * sOut;
  const int t = threadIdx.x;

  const int lr = t >> 2;            // 0..63 (input row)
  const int lcb = (t & 3) << 2;     // float4 col base
#pragma unroll
  for (int i = 0; i < 4; ++i) {
    const int col = lcb + i * 16;
    *(float4*)&tile[lr][col] = *(const float4*)(in + (long long)(r0 + lr) * Cc + c0 + col);
  }
  __syncthreads();

  const int cc = t >> 2;            // 0..63 (output row = input col)
  const int rq = (t & 3) << 3;      // 0,8,16,24
#pragma unroll
  for (int i = 0; i < 2; ++i) {
    const int rr = rq + i * 32;
    s8v o;
#pragma unroll
    for (int j = 0; j < 8; ++j) o[j] = f2bs(tile[rr + j][cc]);
    *(s8v*)(out + (long long)(c0 + cc) * R + r0 + rr) = o;
  }
}

// ---------------- merged prep: bncoef + all weight casts + qdup ----------------
__global__ void prepw(const float* __restrict__ pwb, const float* __restrict__ bng,
                      const float* __restrict__ bnb, const float* __restrict__ bnm,
                      const float* __restrict__ bnv, float* __restrict__ bns,
                      float* __restrict__ bnh,
                      const float* __restrict__ pw_w, short* __restrict__ pw_wb,
                      const float* __restrict__ inp_w, short* __restrict__ inp_wb,
                      const float* __restrict__ q_w, short* __restrict__ q_wb2,
                      const float* __restrict__ k_w, short* __restrict__ k_wb,
                      const float* __restrict__ op_w, short* __restrict__ op_wb)
{
  const int bx = blockIdx.x, t = threadIdx.x;
  if (bx == 0) {
    const float inv = rsqrtf(bnv[t] + 1e-5f);
    const float sc = bng[t] * inv;
    bns[t] = sc;
    bnh[t] = (pwb[t] - bnm[t]) * sc + bnb[t];
    return;
  }
  int i = (bx - 1) * 256 + t;
  if (i < 81920) { pw_wb[i] = f2bs(pw_w[i]); return; }
  i -= 81920;
  if (i < 65536) { inp_wb[i] = f2bs(inp_w[i]); return; }
  i -= 65536;
  if (i < 65536) {
    const short v = f2bs(q_w[i]);
    const int c = i >> 8, e = i & 255;
    q_wb2[c * 512 + e] = v;
    q_wb2[c * 512 + 256 + e] = v;
    return;
  }
  i -= 65536;
  if (i < 65536) { k_wb[i] = f2bs(k_w[i]); return; }
  i -= 65536;
  op_wb[i] = f2bs(op_w[i]);
}

// ---------------- G fp32 -> hi/lo bf16 pair ----------------
__global__ void ghilo(const float* __restrict__ G, short* __restrict__ g2)
{
  const long long i = (long long)blockIdx.x * 256 + threadIdx.x;  // < 32*65536
  const float g = G[i];
  const short h = f2bs(g);
  const short l = f2bs(g - bs2f(h));
  const long long row = i >> 8;
  const int e = (int)(i & 255);
  g2[row * 512 + e] = h;
  g2[row * 512 + 256 + e] = l;
}

// ===========================================================================
// depthwise 3x3 over concat([corr(64), d(256)]), [N,ch] layout.
// Wave remap: lane&7 = channel-group-sub (8 cg per wave), lane>>3 = x-column.
// -> weight LDS reads broadcast across 8 x-lanes, <=2-way bank aliasing (free).
// Each thread: 8 channels x 4 vertical pixels.
// grid (160, B_), block 256 (4 waves; wid = bx*4+wv in [0,640)).
// ===========================================================================
__global__ __launch_bounds__(256) void dwconv5(const short* __restrict__ corr,
                                               const short* __restrict__ dt,
                                               const float* __restrict__ wgt,
                                               const float* __restrict__ bias,
                                               short* __restrict__ outp)
{
  __shared__ __align__(16) float wl[9 * IN_];
  __shared__ __align__(16) float bl[IN_];
  const int tid = threadIdx.x;
  for (int i = tid; i < 9 * IN_; i += 256) {
    const int ch = i / 9, tap = i % 9;
    wl[tap * IN_ + ch] = wgt[i];
  }
  for (int i = tid; i < IN_; i += 256) bl[i] = bias[i];
  __syncthreads();

  const int lane = tid & 63;
  const int wv = tid >> 6;
  const int cgsub = lane & 7;
  const int xsub = lane >> 3;

  const int wid = blockIdx.x * 4 + wv;       // 0..639
  const int b = blockIdx.y;
  const int cgo = wid % 5;                   // 0..4 (wave-uniform)
  const int rest = wid / 5;                  // 0..127
  const int x = ((rest & 7) << 3) + xsub;    // 0..63
  const int y0 = (rest >> 3) << 2;           // 0..60

  const int cg = cgo * 8 + cgsub;
  const int ch0 = cg * 8;

  const short* base;
  int ldch, c0;
  if (cgo == 0) { base = corr + (long long)b * N_ * K_; ldch = K_; c0 = ch0; }
  else          { base = dt   + (long long)b * N_ * C_; ldch = C_; c0 = ch0 - K_; }

  float acc[4][8];
  {
    float4 bv0 = *(const float4*)&bl[ch0];
    float4 bv1 = *(const float4*)&bl[ch0 + 4];
#pragma unroll
    for (int p = 0; p < 4; ++p) {
      acc[p][0] = bv0.x; acc[p][1] = bv0.y; acc[p][2] = bv0.z; acc[p][3] = bv0.w;
      acc[p][4] = bv1.x; acc[p][5] = bv1.y; acc[p][6] = bv1.z; acc[p][7] = bv1.w;
    }
  }

#pragma unroll
  for (int dx = -1; dx <= 1; ++dx) {
    const int xx = x + dx;
    if (xx < 0 || xx >= W_) continue;

    float wv3[3][8];
#pragma unroll
    for (int dy1 = 0; dy1 < 3; ++dy1) {
      float4 wa = *(const float4*)&wl[(dy1 * 3 + (dx + 1)) * IN_ + ch0];
      float4 wb = *(const float4*)&wl[(dy1 * 3 + (dx + 1)) * IN_ + ch0 + 4];
      wv3[dy1][0] = wa.x; wv3[dy1][1] = wa.y; wv3[dy1][2] = wa.z; wv3[dy1][3] = wa.w;
      wv3[dy1][4] = wb.x; wv3[dy1][5] = wb.y; wv3[dy1][6] = wb.z; wv3[dy1][7] = wb.w;
    }

    s8v v[6];
#pragma unroll
    for (int ri = 0; ri < 6; ++ri) {
      const int yy = y0 - 1 + ri;
      if (yy >= 0 && yy < H_)
        v[ri] = *(const s8v*)(base + (long long)(yy * W_ + xx) * ldch + c0);
      else
        v[ri] = (s8v)0;
    }

#pragma unroll
    for (int ri = 0; ri < 6; ++ri) {
      float f[8];
#pragma unroll
      for (int j = 0; j < 8; ++j) f[j] = bs2f(v[ri][j]);
#pragma unroll
      for (int dy1 = 0; dy1 < 3; ++dy1) {
        const int p = ri - dy1;
        if (p < 0 || p > 3) continue;
#pragma unroll
        for (int j = 0; j < 8; ++j)
          acc[p][j] = fmaf(wv3[dy1][j], f[j], acc[p][j]);
      }
    }
  }

#pragma unroll
  for (int p = 0; p < 4; ++p) {
    s8v o;
#pragma unroll
    for (int j = 0; j < 8; ++j) o[j] = f2bs(acc[p][j]);
    *(s8v*)(outp + ((long long)b * N_ + (y0 + p) * W_ + x) * IN_ + ch0) = o;
  }
}

// ---------------- column sums of px_b [N, C] -> r[b, c] (atomic) ----------------
__global__ void colsum(const short* __restrict__ px, float* __restrict__ r)
{
  const int b = blockIdx.y, c = threadIdx.x, chunk = blockIdx.x;
  const short* p = px + (long long)b * N_ * C_ + (long long)chunk * 512 * C_;
  float s = 0.f;
  for (int n = 0; n < 512; ++n) s += bs2f(p[(long long)n * C_ + c]);
  atomicAdd(&r[b * C_ + c], s);
}

// ---------------- small fused kernels ----------------
__global__ void uwker(const float* __restrict__ qw, const float* __restrict__ kw,
                      const float* __restrict__ r, float* __restrict__ u,
                      float* __restrict__ w)
{
  const int b = blockIdx.x, c = threadIdx.x;
  __shared__ float rl[256];
  rl[c] = r[b * C_ + c];
  __syncthreads();
  float su = 0.f, sw = 0.f;
  for (int f = 0; f < C_; ++f) {
    const float rv = rl[f];
    su = fmaf(qw[c * C_ + f], rv, su);
    sw = fmaf(kw[c * C_ + f], rv, sw);
  }
  u[b * C_ + c] = su;
  w[b * C_ + c] = sw;
}

// att buffer holds UNscaled logits (T1 @ k_w^T); scale by 1/16 here.
__global__ void fixsoftmax(float* __restrict__ att, const float* __restrict__ u,
                           const float* __restrict__ w, const float* __restrict__ qb,
                           const float* __restrict__ kb)
{
  const int c = blockIdx.x, b = blockIdx.y, d = threadIdx.x;
  const long long base = ((long long)b * C_ + c) * (long long)C_;
  const float qbc = qb[c];
  float val = 0.0625f * (att[base + d] + u[b * C_ + c] * kb[d] + qbc * w[b * C_ + d] +
                         (float)N_ * qbc * kb[d]);
  __shared__ float red[256];
  red[d] = val;
  __syncthreads();
  for (int k = 128; k > 0; k >>= 1) {
    if (d < k) red[d] = fmaxf(red[d], red[d + k]);
    __syncthreads();
  }
  const float mx = red[0];
  __syncthreads();
  const float e = expf(val - mx);
  red[d] = e;
  __syncthreads();
  for (int k = 128; k > 0; k >>= 1) {
    if (d < k) red[d] += red[d + k];
    __syncthreads();
  }
  att[base + d] = e / red[0];
}

__global__ void m2bker(const float* __restrict__ att, const float* __restrict__ vb,
                       float* __restrict__ m2b)
{
  const int b = blockIdx.x, d = threadIdx.x;
  const float* a = att + (long long)b * C_ * C_;
  float s = 0.f;
  for (int c = 0; c < C_; ++c) s = fmaf(a[c * C_ + d], vb[c], s);
  m2b[b * C_ + d] = s;
}

__global__ void b3ker(const float* __restrict__ opw, const float* __restrict__ m2b,
                      const float* __restrict__ opb, float* __restrict__ b3)
{
  const int b = blockIdx.x, o = threadIdx.x;
  __shared__ float m[256];
  m[o] = m2b[b * C_ + o];
  __syncthreads();
  float s = opb[o];
  for (int d = 0; d < C_; ++d) s = fmaf(opw[o * C_ + d], m[d], s);
  b3[b * C_ + o] = s;
}

// ===========================================================================
extern "C" void kernel_launch(void* const* d_in, const int* in_sizes, int n_in,
                              void* d_out, int out_size, void* d_ws, size_t ws_size,
                              hipStream_t stream)
{
  (void)in_sizes; (void)n_in; (void)out_size; (void)ws_size;
  const float* z     = (const float*)d_in[0];
  const float* x     = (const float*)d_in[1];
  const float* dimg  = (const float*)d_in[2];
  const float* dw_w  = (const float*)d_in[3];
  const float* dw_b  = (const float*)d_in[4];
  const float* pw_w  = (const float*)d_in[5];
  const float* pw_b  = (const float*)d_in[6];
  const float* bn_g  = (const float*)d_in[7];
  const float* bn_b  = (const float*)d_in[8];
  const float* bn_m  = (const float*)d_in[9];
  const float* bn_v  = (const float*)d_in[10];
  const float* inp_w = (const float*)d_in[11];
  const float* inp_b = (const float*)d_in[12];
  const float* q_w   = (const float*)d_in[13];
  const float* q_b   = (const float*)d_in[14];
  const float* k_w   = (const float*)d_in[15];
  const float* k_b   = (const float*)d_in[16];
  const float* v_w   = (const float*)d_in[17];
  const float* v_b   = (const float*)d_in[18];
  const float* op_w  = (const float*)d_in[19];
  const float* op_b  = (const float*)d_in[20];
  float* out = (float*)d_out;

  char* ws = (char*)d_ws;
  short* xt    = (short*)(ws + OB_XT);
  short* zt    = (short*)(ws + OB_ZT);
  short* dws   = (short*)(ws + OB_DWS);
  short* dt    = (short*)(ws + OB_DT);
  short* px_b  = (short*)(ws + OB_PX);
  short* corr  = (short*)(ws + OB_CORR);
  float* G     = (float*)(ws + OB_G);
  short* Gb2   = (short*)(ws + OB_GB2);
  short* s_b   = (short*)(ws + OB_S);
  short* pxT   = (short*)(ws + OB_PXT);
  float* att   = (float*)(ws + OB_ATT);
  short* M2scr = (short*)(ws + OB_M2);
  short* pw_wb = (short*)(ws + OB_PWW);
  short* inp_wb= (short*)(ws + OB_INPW);
  short* M3b   = (short*)(ws + OB_M3B);
  float* r     = (float*)(ws + OB_R);
  float* u     = (float*)(ws + OB_U);
  float* w2    = (float*)(ws + OB_W2);
  float* m2b   = (float*)(ws + OB_M2B);
  float* b3    = (float*)(ws + OB_B3);
  float* bns   = (float*)(ws + OB_BNS);
  float* bnh   = (float*)(ws + OB_BNH);
  short* q_wb2 = (short*)(ws + OB_QW2);
  short* k_wb  = (short*)(ws + OB_KWB);
  short* op_wb = (short*)(ws + OB_OPWB);
  short* T1b   = (short*)(ws + OB_T1B);
  short* attT  = (short*)(ws + OB_ATTT);
  short* M2T   = (short*)(ws + OB_M2T);
  short* v_wT  = (short*)(ws + OB_VWT);

  const long long sNC = (long long)N_ * C_;
  const long long sNK = (long long)N_ * K_;
  const long long sNI = (long long)N_ * IN_;
  const long long sCC = (long long)C_ * C_;

  // --- prep: BN fold + all small weight casts in ONE kernel ---
  prepw<<<1345, 256, 0, stream>>>(pw_b, bn_g, bn_b, bn_m, bn_v, bns, bnh,
                                  pw_w, pw_wb, inp_w, inp_wb, q_w, q_wb2,
                                  k_w, k_wb, op_w, op_wb);
  tcast8<<<dim3(4, 4, 1), 256, 0, stream>>>(v_w, v_wT, C_, C_, 0, 0);
  tcast8<<<dim3(N_ / 64, C_ / 64, B_), 256, 0, stream>>>(x, xt, C_, N_, sNC, sNC);
  tcast8<<<dim3(1, C_ / 64, B_), 256, 0, stream>>>(z, zt, C_, K_, (long long)C_ * K_,
                                                   (long long)C_ * K_);
  tcast8<<<dim3(N_ / 64, C_ / 64, B_), 256, 0, stream>>>(dimg, dt, C_, N_, sNC, sNC);

  // --- corr[n,k] = sum_c xt[n,c] zt[k,c] ---
  mgemm<64, 1, 1><<<dim3(1, 32, B_), 256, 0, stream>>>(
      xt, C_, sNC, zt, C_, (long long)K_ * C_, corr, K_, sNK, C_,
      nullptr, nullptr, nullptr, nullptr, 0, 0, nullptr, 0, 0);

  // --- depthwise 3x3, output dws [n, 320] bf16 ---
  dwconv5<<<dim3(160, B_), 256, 0, stream>>>(corr, dt, dw_w, dw_b, dws);

  // --- s[n,o] = relu(bn(sum_i dws[n,i] pw_w[o,i])) ---
  mgemm<128, 1, (1 | 4)><<<dim3(2, 32, B_), 256, 0, stream>>>(
      dws, IN_, sNI, pw_wb, IN_, 0, s_b, C_, sNC, IN_,
      bns, bnh, nullptr, nullptr, 0, 0, nullptr, 0, 0);

  // --- px[n,o] = sum_i s[n,i] inp_w[o,i] + inp_b : bf16 + transposed copy ---
  mgemm<128, 1, (1 | 2 | 32)><<<dim3(2, 32, B_), 256, 0, stream>>>(
      s_b, C_, sNC, inp_wb, C_, 0, px_b, C_, sNC, C_,
      inp_b, nullptr, nullptr, nullptr, 0, 0, pxT, N_, sNC);

  // --- r[b,c] = column sums of px ---
  hipMemsetAsync(r, 0, B_ * C_ * sizeof(float), stream);
  colsum<<<dim3(8, B_), 256, 0, stream>>>(px_b, r);

  // --- G = pxT @ pxT^T (K=4096, split-K=8, fp32 atomics) ---
  hipMemsetAsync(G, 0, (size_t)B_ * C_ * C_ * sizeof(float), stream);
  mgemm<128, 8, 64><<<dim3(2, 2, B_ * 8), 256, 0, stream>>>(
      pxT, N_, sNC, pxT, N_, sNC, G, C_, sCC, N_ / 8,
      nullptr, nullptr, nullptr, nullptr, 0, 0, nullptr, 0, 0);

  // --- G -> hi/lo bf16 pair ---
  ghilo<<<8192, 256, 0, stream>>>(G, Gb2);

  // --- rank-1 pieces ---
  uwker<<<B_, 256, 0, stream>>>(q_w, k_w, r, u, w2);

  // --- T1[c,g] = sum_f q_w[c,f] G[f,g] : MFMA K=512 (hi+lo), out bf16 ---
  mgemm<128, 1, 1><<<dim3(2, 2, B_), 256, 0, stream>>>(
      q_wb2, 512, 0, Gb2, 512, 256LL * 512, T1b, C_, sCC, 512,
      nullptr, nullptr, nullptr, nullptr, 0, 0, nullptr, 0, 0);

  // --- logits[c,d] = sum_g T1[c,g] k_w[d,g] (unscaled) : fp32 out ---
  mgemm<128, 1, 0><<<dim3(2, 2, B_), 256, 0, stream>>>(
      T1b, C_, sCC, k_wb, C_, 0, att, C_, sCC, C_,
      nullptr, nullptr, nullptr, nullptr, 0, 0, nullptr, 0, 0);

  fixsoftmax<<<dim3(C_, B_), 256, 0, stream>>>(att, u, w2, q_b, k_b);

  // --- attT[d][c] = att[c][d] bf16 ---
  tcast8<<<dim3(4, 4, B_), 256, 0, stream>>>(att, attT, C_, C_, sCC, sCC);

  // --- M2[d][f] = sum_c att[c,d] v_w[c,f] = attT @ v_wT^T ; write M2T[f][d] bf16 ---
  mgemm<128, 1, (1 | 32)><<<dim3(2, 2, B_), 256, 0, stream>>>(
      attT, C_, sCC, v_wT, C_, 0, M2scr, C_, sCC, C_,
      nullptr, nullptr, nullptr, nullptr, 0, 0, M2T, C_, sCC);

  // --- M3[o][f] = sum_d op_w[o,d] M2[d,f] : bf16 out ---
  mgemm<128, 1, 1><<<dim3(2, 2, B_), 256, 0, stream>>>(
      op_wb, C_, 0, M2T, C_, sCC, M3b, C_, sCC, C_,
      nullptr, nullptr, nullptr, nullptr, 0, 0, nullptr, 0, 0);

  m2bker<<<B_, 256, 0, stream>>>(att, v_b, m2b);
  b3ker<<<B_, 256, 0, stream>>>(op_w, m2b, op_b, b3);

  // --- out[o,n] = sum_f M3[o,f] px[n,f] + b3[b,o] + s[n,o] : fp32, [b,c,h,w] ---
  mgemm<128, 1, (8 | 16)><<<dim3(32, 2, B_), 256, 0, stream>>>(
      M3b, C_, sCC, px_b, C_, sNC, out, N_, sNC, C_,
      nullptr, nullptr, b3, s_b, C_, sNC, nullptr, 0, 0);
}